// Round 6
// baseline (1063.782 us; speedup 1.0000x reference)
//
#include <hip/hip_runtime.h>

typedef unsigned short u16;
typedef __bf16 bf16x8 __attribute__((ext_vector_type(8)));
typedef float f32x4 __attribute__((ext_vector_type(4)));

__device__ __forceinline__ float bf2f(u16 u) {
  union { unsigned int i; float f; } v; v.i = ((unsigned int)u) << 16; return v.f;
}
__device__ __forceinline__ u16 f2bf(float f) {
  union { float f; unsigned int i; } v; v.f = f;
  unsigned int i = v.i;
  return (u16)((i + 0x7fffu + ((i >> 16) & 1u)) >> 16);  // RNE
}
__device__ __forceinline__ float ldf(const float* p) { return *p; }
__device__ __forceinline__ float ldf(const u16* p) { return bf2f(*p); }

// ---------------- weight transpose + cast: Wt[n*K+k] = bf16(W[k*N+n]) ----
__global__ void transpose_kernel(const float* __restrict__ W, u16* __restrict__ Wt,
                                 int K, int N) {
  int idx = blockIdx.x * 256 + threadIdx.x;
  if (idx >= K * N) return;
  int k = idx / N, n = idx % N;
  Wt[n * K + k] = f2bf(W[idx]);
}

// ---------------- layernorm over C=576, 4 rows/block (1 wave each) -------
template <typename T>
__global__ __launch_bounds__(256) void ln_kernel(const T* __restrict__ x,
                                                 const float* __restrict__ w,
                                                 const float* __restrict__ b,
                                                 u16* __restrict__ out) {
  int wave = threadIdx.x >> 6, lane = threadIdx.x & 63;
  long row = (long)blockIdx.x * 4 + wave;
  const T* xr = x + row * 576;
  float v[9];
  float sum = 0.f;
  #pragma unroll
  for (int i = 0; i < 9; ++i) { v[i] = ldf(&xr[lane + i * 64]); sum += v[i]; }
  #pragma unroll
  for (int off = 32; off; off >>= 1) sum += __shfl_xor(sum, off);
  float mean = sum * (1.0f / 576.0f);
  float var = 0.f;
  #pragma unroll
  for (int i = 0; i < 9; ++i) { float d = v[i] - mean; var += d * d; }
  #pragma unroll
  for (int off = 32; off; off >>= 1) var += __shfl_xor(var, off);
  float rstd = rsqrtf(var * (1.0f / 576.0f) + 1e-5f);
  u16* outr = out + row * 576;
  #pragma unroll
  for (int i = 0; i < 9; ++i) {
    int c = lane + i * 64;
    outr[c] = f2bf((v[i] - mean) * rstd * w[c] + b[c]);
  }
}

// ---------------- DMlp gather: pixelshuffle(3) + reflpad(2) + masked unfold
// chunk-local: ln2 points at chunk start (whole batches), b chunk-relative.
__constant__ int c_di[25] = {0,0,0, 1,1,1, 2,2,2, 3,3,3,3,3,3,3, 4,4,4, 5,5,5, 6,6,6};
__constant__ int c_dj[25] = {0,3,6, 1,3,5, 2,3,4, 0,1,2,3,4,5,6, 2,3,4, 1,3,5, 0,3,6};

__device__ __forceinline__ int refl168(int t) {
  return t < 0 ? -t : (t >= 168 ? 334 - t : t);
}

__global__ __launch_bounds__(256) void gather_kernel(const u16* __restrict__ ln2,
                                                     u16* __restrict__ cols) {
  int idx = blockIdx.x * 256 + threadIdx.x;
  int f = idx % 1600;
  int n_ = idx / 1600;            // b*3136 + i*56 + j  (b chunk-relative)
  int bj = n_ % 3136, b = n_ / 3136;
  int i = bj / 56, j = bj % 56;
  int p = f % 25, nf = f / 25;
  int R  = refl168(c_di[p] + 3 * i - 2);
  int Cc = refl168(c_dj[p] + 3 * j - 2);
  int h2 = R / 3, a = R - 3 * h2;
  int w2 = Cc / 3, b2 = Cc - 3 * w2;
  long src = ((long)b * 3136 + h2 * 56 + w2) * 576 + nf * 9 + a * 3 + b2;
  cols[idx] = ln2[src];
}

// ---------------- window attention, one block per (window, head) ---------
__global__ __launch_bounds__(256) void attn_kernel(const u16* __restrict__ qkv,
                                                   const float* __restrict__ rpb,
                                                   u16* __restrict__ obuf) {
  int h = blockIdx.y;            // 0..5
  int wi = blockIdx.x;
  int b = wi >> 6, w = wi & 63, wr = w >> 3, wc = w & 7;
  __shared__ float Qs[49 * 96];  // reused for V
  __shared__ float Ks[49 * 96];
  __shared__ float Ss[49 * 50];
  int tid = threadIdx.x;
  const float scale = 0.1020620726159658f;  // 96^-0.5

  for (int idx = tid; idx < 49 * 96; idx += 256) {
    int t = idx / 96, d = idx - t * 96;
    int tr = t / 7, tc = t - tr * 7;
    long roff = ((long)b * 3136 + (wr * 7 + tr) * 56 + wc * 7 + tc) * 1728 + h * 96 + d;
    Qs[idx] = bf2f(qkv[roff]) * scale;
    Ks[idx] = bf2f(qkv[roff + 576]);
  }
  __syncthreads();
  for (int idx = tid; idx < 2401; idx += 256) {
    int i = idx / 49, j = idx - i * 49;
    float s = 0.f;
    #pragma unroll 8
    for (int d = 0; d < 96; ++d) s += Qs[i * 96 + d] * Ks[j * 96 + d];
    int yi = i / 7, xi = i - yi * 7, yj = j / 7, xj = j - yj * 7;
    int rel = (yi - yj + 6) * 13 + (xi - xj + 6);
    s += rpb[rel * 6 + h];
    Ss[i * 50 + j] = s;
  }
  __syncthreads();
  if (tid < 49) {
    float mx = -1e30f;
    for (int j = 0; j < 49; ++j) mx = fmaxf(mx, Ss[tid * 50 + j]);
    float sum = 0.f;
    for (int j = 0; j < 49; ++j) { float e = __expf(Ss[tid * 50 + j] - mx); Ss[tid * 50 + j] = e; sum += e; }
    float inv = 1.0f / sum;
    for (int j = 0; j < 49; ++j) Ss[tid * 50 + j] *= inv;
  }
  __syncthreads();
  for (int idx = tid; idx < 49 * 96; idx += 256) {
    int t = idx / 96, d = idx - t * 96;
    int tr = t / 7, tc = t - tr * 7;
    Qs[idx] = bf2f(qkv[((long)b * 3136 + (wr * 7 + tr) * 56 + wc * 7 + tc) * 1728 + 1152 + h * 96 + d]);
  }
  __syncthreads();
  for (int idx = tid; idx < 49 * 96; idx += 256) {
    int i = idx / 96, d = idx - i * 96;
    int tr = i / 7, tc = i - tr * 7;
    float o = 0.f;
    #pragma unroll 7
    for (int j = 0; j < 49; ++j) o += Ss[i * 50 + j] * Qs[j * 96 + d];
    obuf[((long)b * 3136 + (wr * 7 + tr) * 56 + wc * 7 + tc) * 576 + h * 96 + d] = f2bf(o);
  }
}

// ---------------- bf16 MFMA GEMM: C(M,N) = A(M,K) @ Bt(N,K)^T + epi ------
// tile 128x64x32, 256 threads (4 waves)
// EPI: 0 = +bias ; 1 = +bias, exact GELU ; 2 = +bias, +res
// TR: residual elem type (float or u16). TO: output elem type (u16 or float).
template <int EPI, typename TR, typename TO>
__global__ __launch_bounds__(256) void gemm_kernel(const u16* __restrict__ A,
                                                   const u16* __restrict__ Bt,
                                                   const float* __restrict__ bias,
                                                   const TR* __restrict__ res,
                                                   TO* __restrict__ C,
                                                   int M, int N, int K) {
  __shared__ u16 As[128 * 40];
  __shared__ u16 Bs[64 * 40];
  int n0 = blockIdx.x * 64;
  int m0 = blockIdx.y * 128;
  int tid = threadIdx.x;
  int lane = tid & 63, wv = tid >> 6;
  int quad = lane >> 4, l15 = lane & 15;
  f32x4 acc[2][4] = {};

  for (int k0 = 0; k0 < K; k0 += 32) {
    #pragma unroll
    for (int it = 0; it < 2; ++it) {
      int idx = (tid + it * 256) * 8;
      int r = idx >> 5, kk = idx & 31;
      uint4 v = *(const uint4*)(A + (long)(m0 + r) * K + k0 + kk);
      *(uint4*)(&As[r * 40 + kk]) = v;
    }
    {
      int idx = tid * 8;
      int r = idx >> 5, kk = idx & 31;
      uint4 v = *(const uint4*)(Bt + (long)(n0 + r) * K + k0 + kk);
      *(uint4*)(&Bs[r * 40 + kk]) = v;
    }
    __syncthreads();
    bf16x8 a0 = *(const bf16x8*)(&As[(wv * 32 + l15) * 40 + quad * 8]);
    bf16x8 a1 = *(const bf16x8*)(&As[(wv * 32 + 16 + l15) * 40 + quad * 8]);
    #pragma unroll
    for (int nt = 0; nt < 4; ++nt) {
      bf16x8 bf = *(const bf16x8*)(&Bs[(nt * 16 + l15) * 40 + quad * 8]);
      acc[0][nt] = __builtin_amdgcn_mfma_f32_16x16x32_bf16(a0, bf, acc[0][nt], 0, 0, 0);
      acc[1][nt] = __builtin_amdgcn_mfma_f32_16x16x32_bf16(a1, bf, acc[1][nt], 0, 0, 0);
    }
    __syncthreads();
  }
  #pragma unroll
  for (int mt = 0; mt < 2; ++mt)
    #pragma unroll
    for (int nt = 0; nt < 4; ++nt)
      #pragma unroll
      for (int r = 0; r < 4; ++r) {
        int row = m0 + wv * 32 + mt * 16 + quad * 4 + r;
        int col = n0 + nt * 16 + l15;
        float v = acc[mt][nt][r] + bias[col];
        if (EPI == 1) v = 0.5f * v * (1.0f + erff(v * 0.70710678118654752f));
        if (EPI == 2) v += ldf(&res[(long)row * N + col]);
        long off = (long)row * N + col;
        if (sizeof(TO) == 2) ((u16*)C)[off] = f2bf(v);
        else                 ((float*)C)[off] = v;
      }
}

// ---------------- host launch -------------------------------------------
// Inputs fp32, OUTPUT FP32 (round-5 forensics). ws peak ~93.8 MB.
// phase 1 (ln1/qkv/attn/proj) in 2 batch-halves, phase 2 in 4 batch-quarters.
extern "C" void kernel_launch(void* const* d_in, const int* in_sizes, int n_in,
                              void* d_out, int out_size, void* d_ws, size_t ws_size,
                              hipStream_t stream) {
  const float* x      = (const float*)d_in[0];
  const float* n1w    = (const float*)d_in[1];
  const float* n1b    = (const float*)d_in[2];
  const float* qkv_w  = (const float*)d_in[3];
  const float* qkv_b  = (const float*)d_in[4];
  const float* rpb    = (const float*)d_in[5];
  const float* proj_w = (const float*)d_in[6];
  const float* proj_b = (const float*)d_in[7];
  const float* n2w    = (const float*)d_in[8];
  const float* n2b    = (const float*)d_in[9];
  const float* fc1_w  = (const float*)d_in[10];
  const float* fc1_b  = (const float*)d_in[11];
  const float* fc2_w  = (const float*)d_in[12];
  const float* fc2_b  = (const float*)d_in[13];

  char* ws = (char*)d_ws;
  u16* wt_qkv  = (u16*)(ws + 0);           // 1728x576
  u16* wt_proj = (u16*)(ws + 1990656);     // 576x576
  u16* wt_fc1  = (u16*)(ws + 2654208);     // 1024x1600
  u16* wt_fc2  = (u16*)(ws + 5931008);     // 576x1024
  char* qkvpool = ws + 7110656;            // 43,352,064 B (12544x1728 bf16)
  char* lnpool  = ws + 50462720;           // 14,450,688 B (12544x576 bf16)
  u16* x1buf    = (u16*)(ws + 64913408);   // 25088x576 bf16 (end 93,814,784)

  transpose_kernel<<<3888, 256, 0, stream>>>(qkv_w, wt_qkv, 576, 1728);
  transpose_kernel<<<1296, 256, 0, stream>>>(proj_w, wt_proj, 576, 576);
  transpose_kernel<<<6400, 256, 0, stream>>>(fc1_w, wt_fc1, 1600, 1024);
  transpose_kernel<<<2304, 256, 0, stream>>>(fc2_w, wt_fc2, 1024, 576);

  // ---------- phase 1: two halves of 4 batches (12544 rows) ----------
  for (int h = 0; h < 2; ++h) {
    const long r0 = (long)h * 12544;
    u16* lnb  = (u16*)lnpool;          // ln1 out, then reused as attn out
    u16* qkvb = (u16*)qkvpool;
    ln_kernel<float><<<3136, 256, 0, stream>>>(x + r0 * 576, n1w, n1b, lnb);
    gemm_kernel<0, float, u16><<<dim3(27, 98), 256, 0, stream>>>(
        lnb, wt_qkv, qkv_b, (const float*)nullptr, qkvb, 12544, 1728, 576);
    attn_kernel<<<dim3(256, 6), 256, 0, stream>>>(qkvb, rpb, lnb);
    gemm_kernel<2, float, u16><<<dim3(9, 98), 256, 0, stream>>>(
        lnb, wt_proj, proj_b, x + r0 * 576, x1buf + r0 * 576, 12544, 576, 576);
  }

  // ---------- phase 2: four quarters of 2 batches (6272 rows) ----------
  for (int q = 0; q < 4; ++q) {
    const long r0 = (long)q * 6272;
    u16* ln2b  = (u16*)lnpool;                    //  7,225,344 B
    u16* colsb = (u16*)qkvpool;                   // 20,070,400 B
    u16* hb    = (u16*)(qkvpool + 20070400);      // 12,845,056 B
    ln_kernel<u16><<<1568, 256, 0, stream>>>(x1buf + r0 * 576, n2w, n2b, ln2b);
    gather_kernel<<<39200, 256, 0, stream>>>(ln2b, colsb);
    gemm_kernel<1, float, u16><<<dim3(16, 49), 256, 0, stream>>>(
        colsb, wt_fc1, fc1_b, (const float*)nullptr, hb, 6272, 1024, 1600);
    gemm_kernel<2, u16, float><<<dim3(9, 49), 256, 0, stream>>>(
        hb, wt_fc2, fc2_b, x1buf + r0 * 576, (float*)d_out + r0 * 576,
        6272, 576, 1024);
  }
}